// Round 1
// baseline (2274.754 us; speedup 1.0000x reference)
//
#include <hip/hip_runtime.h>
#include <math.h>

#define BB 64
#define TT 1500
#define DD 1024
#define AA 512
#define CC 10
#define KW 101
#define PADW 50
#define SHARP 2.0f

#define TM 64
#define KT 16

// ---------------------------------------------------------------------------
// conv_feat[b,t,c] = sum_k att[b, t+k-50] * ck[c,k]   (zero-padded)
// ---------------------------------------------------------------------------
__global__ void conv_kernel(const float* __restrict__ att,
                            const float* __restrict__ ck,
                            float* __restrict__ cf) {
    __shared__ float ck_s[CC * KW];
    int tid = threadIdx.x;
    for (int i = tid; i < CC * KW; i += blockDim.x) ck_s[i] = ck[i];
    __syncthreads();
    int b = blockIdx.y;
    int t = blockIdx.x * blockDim.x + tid;
    if (t >= TT) return;
    float acc[CC];
#pragma unroll
    for (int c = 0; c < CC; ++c) acc[c] = 0.f;
    const float* arow = att + b * TT;
    int k0 = PADW - t; if (k0 < 0) k0 = 0;
    int k1 = TT + PADW - t; if (k1 > KW) k1 = KW;
    for (int k = k0; k < k1; ++k) {
        float av = arow[t + k - PADW];
#pragma unroll
        for (int c = 0; c < CC; ++c) acc[c] = fmaf(av, ck_s[c * KW + k], acc[c]);
    }
    float* o = cf + (size_t)(b * TT + t) * CC;
#pragma unroll
    for (int c = 0; c < CC; ++c) o[c] = acc[c];
}

// ---------------------------------------------------------------------------
// dec_proj[b,a] = W_b[a] + sum_d dec[b,d] * W_w[D+d, a]
// ---------------------------------------------------------------------------
__global__ void decproj_kernel(const float* __restrict__ dec,
                               const float* __restrict__ Ww,
                               const float* __restrict__ Wb,
                               float* __restrict__ dp) {
    int b = blockIdx.x;
    int a = threadIdx.x;            // blockDim = 512
    const float* dr = dec + b * DD;
    const float* w = Ww + (size_t)DD * AA + a;
    float acc = Wb[a];
    for (int d = 0; d < DD; ++d) acc = fmaf(dr[d], w[(size_t)d * AA], acc);
    dp[b * AA + a] = acc;
}

// ---------------------------------------------------------------------------
// energy[b,t] = 2 * sum_a tanh( enc[b,t,:]@W1[:,a] + dp[b,a] + cf[b,t,:]@Wc[:,a] ) * V[a]
// 64-row x 512-col x K16 LDS-tiled fp32 GEMM, fused epilogue.
// block 256 = (tx 16) x (ty 16); thread owns rows ty*4..+3, cols {ch*128+tx*8+j}
// ---------------------------------------------------------------------------
__global__ __launch_bounds__(256, 2) void energy_kernel(
    const float* __restrict__ enc, const float* __restrict__ Ww,
    const float* __restrict__ Wc, const float* __restrict__ Vw,
    const float* __restrict__ dp, const float* __restrict__ cf,
    float* __restrict__ energy) {
    __shared__ float Ws[KT][AA];        // 32 KB  W1 k-tile
    __shared__ float Es[KT][TM + 4];    // 4.25 KB transposed enc tile
    __shared__ float Wc_s[CC][AA];      // 20 KB
    __shared__ float dp_s[AA];
    __shared__ float V_s[AA];

    int tid = threadIdx.x;
    int b = blockIdx.y;
    int t0 = blockIdx.x * TM;
    int tx = tid & 15, ty = tid >> 4;

    for (int i = tid; i < CC * AA; i += 256) ((float*)Wc_s)[i] = Wc[i];
    for (int i = tid; i < AA; i += 256) { dp_s[i] = dp[b * AA + i]; V_s[i] = Vw[i]; }

    float acc[4][32];
#pragma unroll
    for (int i = 0; i < 4; ++i)
#pragma unroll
        for (int j = 0; j < 32; ++j) acc[i][j] = 0.f;

    int r = tid >> 2, kq = tid & 3;                  // staging map: 4 thr/row
    int tg = t0 + r; if (tg > TT - 1) tg = TT - 1;   // clamp tail rows
    const float* esrc = enc + (size_t)(b * TT + tg) * DD + kq * 4;

    for (int kt = 0; kt < DD / KT; ++kt) {
        __syncthreads();
        // stage W1[kt*16 .. +15][0..511] -> Ws   (fully coalesced float4)
        const float* wsrc = Ww + (size_t)(kt * KT) * AA;
#pragma unroll
        for (int i = 0; i < 8; ++i) {
            int f = tid + 256 * i;
            int row = f >> 7, c4 = f & 127;
            *(float4*)&Ws[row][c4 * 4] =
                *(const float4*)&wsrc[(size_t)row * AA + c4 * 4];
        }
        // stage enc tile transposed -> Es
        float4 ev = *(const float4*)&esrc[kt * KT];
        Es[kq * 4 + 0][r] = ev.x;
        Es[kq * 4 + 1][r] = ev.y;
        Es[kq * 4 + 2][r] = ev.z;
        Es[kq * 4 + 3][r] = ev.w;
        __syncthreads();

#pragma unroll
        for (int kk = 0; kk < KT; ++kk) {
            float4 av = *(const float4*)&Es[kk][ty * 4];
            float a0 = av.x, a1 = av.y, a2 = av.z, a3 = av.w;
#pragma unroll
            for (int ch = 0; ch < 4; ++ch) {
                const float* wr = &Ws[kk][ch * 128 + tx * 8];
                float4 b0 = *(const float4*)&wr[0];
                float4 b1 = *(const float4*)&wr[4];
                float bv[8] = {b0.x, b0.y, b0.z, b0.w, b1.x, b1.y, b1.z, b1.w};
#pragma unroll
                for (int j = 0; j < 8; ++j) {
                    acc[0][ch * 8 + j] = fmaf(a0, bv[j], acc[0][ch * 8 + j]);
                    acc[1][ch * 8 + j] = fmaf(a1, bv[j], acc[1][ch * 8 + j]);
                    acc[2][ch * 8 + j] = fmaf(a2, bv[j], acc[2][ch * 8 + j]);
                    acc[3][ch * 8 + j] = fmaf(a3, bv[j], acc[3][ch * 8 + j]);
                }
            }
        }
    }

    // fused epilogue: + dec_proj + conv@Wc, tanh, *V, row-reduce
    float esum[4] = {0.f, 0.f, 0.f, 0.f};
#pragma unroll
    for (int i = 0; i < 4; ++i) {
        int t = t0 + ty * 4 + i;
        int tc = t < TT ? t : TT - 1;
        const float* cfr = cf + (size_t)(b * TT + tc) * CC;
        float cfv[CC];
#pragma unroll
        for (int c = 0; c < CC; ++c) cfv[c] = cfr[c];
#pragma unroll
        for (int ch = 0; ch < 4; ++ch) {
#pragma unroll
            for (int j = 0; j < 8; ++j) {
                int col = ch * 128 + tx * 8 + j;
                float v = acc[i][ch * 8 + j] + dp_s[col];
#pragma unroll
                for (int c = 0; c < CC; ++c) v = fmaf(cfv[c], Wc_s[c][col], v);
                esum[i] += tanhf(v) * V_s[col];
            }
        }
    }
#pragma unroll
    for (int i = 0; i < 4; ++i) {
        float e = esum[i];
        e += __shfl_xor(e, 1);
        e += __shfl_xor(e, 2);
        e += __shfl_xor(e, 4);
        e += __shfl_xor(e, 8);
        int t = t0 + ty * 4 + i;
        if (tx == 0 && t < TT) energy[b * TT + t] = SHARP * e;
    }
}

// ---------------------------------------------------------------------------
// softmax over T per batch row
// ---------------------------------------------------------------------------
__global__ void softmax_kernel(const float* __restrict__ energy,
                               float* __restrict__ att) {
    int b = blockIdx.x, tid = threadIdx.x;
    const float* e = energy + b * TT;
    __shared__ float red[8];
    float m = -1e30f;
    for (int t = tid; t < TT; t += 256) m = fmaxf(m, e[t]);
#pragma unroll
    for (int s = 1; s < 64; s <<= 1) m = fmaxf(m, __shfl_xor(m, s));
    if ((tid & 63) == 0) red[tid >> 6] = m;
    __syncthreads();
    m = fmaxf(fmaxf(red[0], red[1]), fmaxf(red[2], red[3]));
    float s = 0.f;
    for (int t = tid; t < TT; t += 256) s += expf(e[t] - m);
#pragma unroll
    for (int sh = 1; sh < 64; sh <<= 1) s += __shfl_xor(s, sh);
    if ((tid & 63) == 0) red[4 + (tid >> 6)] = s;
    __syncthreads();
    s = red[4] + red[5] + red[6] + red[7];
    float inv = 1.f / s;
    for (int t = tid; t < TT; t += 256) att[b * TT + t] = expf(e[t] - m) * inv;
}

// ---------------------------------------------------------------------------
// context[b,d] = sum_t enc[b,t,d] * att[b,t]   (T split 12-way, atomicAdd)
// ---------------------------------------------------------------------------
#define TCH 125
__global__ void context_kernel(const float* __restrict__ enc,
                               const float* __restrict__ att,
                               float* __restrict__ ctx) {
    int b = blockIdx.x, ch = blockIdx.y;
    int d0 = threadIdx.x * 4;
    int ts = ch * TCH, te = ts + TCH; if (te > TT) te = TT;
    const float* ab = att + b * TT;
    float ax = 0.f, ay = 0.f, az = 0.f, aw = 0.f;
    for (int t = ts; t < te; ++t) {
        float w = ab[t];
        float4 ev = *(const float4*)&enc[(size_t)(b * TT + t) * DD + d0];
        ax = fmaf(w, ev.x, ax);
        ay = fmaf(w, ev.y, ay);
        az = fmaf(w, ev.z, az);
        aw = fmaf(w, ev.w, aw);
    }
    float* o = ctx + b * DD + d0;
    atomicAdd(&o[0], ax);
    atomicAdd(&o[1], ay);
    atomicAdd(&o[2], az);
    atomicAdd(&o[3], aw);
}

// ---------------------------------------------------------------------------
extern "C" void kernel_launch(void* const* d_in, const int* in_sizes, int n_in,
                              void* d_out, int out_size, void* d_ws, size_t ws_size,
                              hipStream_t stream) {
    const float* enc  = (const float*)d_in[0];
    const float* dec  = (const float*)d_in[1];
    const float* attw = (const float*)d_in[2];
    const float* Ww   = (const float*)d_in[3];
    const float* Wb   = (const float*)d_in[4];
    const float* Wc   = (const float*)d_in[5];
    const float* Vw   = (const float*)d_in[6];
    const float* ck   = (const float*)d_in[7];

    float* out = (float*)d_out;
    float* ctx = out;               // [B, D]   (context_vec, flattened)
    float* att = out + BB * DD;     // [B, T]

    float* cf     = (float*)d_ws;                       // B*T*C
    float* dp     = cf + (size_t)BB * TT * CC;          // B*A
    float* energy = dp + (size_t)BB * AA;               // B*T

    hipMemsetAsync(ctx, 0, (size_t)BB * DD * sizeof(float), stream);

    conv_kernel<<<dim3((TT + 255) / 256, BB), 256, 0, stream>>>(attw, ck, cf);
    decproj_kernel<<<BB, AA, 0, stream>>>(dec, Ww, Wb, dp);
    energy_kernel<<<dim3((TT + TM - 1) / TM, BB), 256, 0, stream>>>(
        enc, Ww, Wc, Vw, dp, cf, energy);
    softmax_kernel<<<BB, 256, 0, stream>>>(energy, att);
    context_kernel<<<dim3(BB, 12), 256, 0, stream>>>(enc, att, ctx);
}

// Round 2
// 800.332 us; speedup vs baseline: 2.8423x; 2.8423x over previous
//
#include <hip/hip_runtime.h>
#include <math.h>

#define BB 64
#define TT 1500
#define DD 1024
#define AA 512
#define CC 10
#define KW 101
#define PADW 50
#define SHARP 2.0f

typedef __attribute__((ext_vector_type(8))) unsigned short u16x8;
typedef __attribute__((ext_vector_type(8))) short bf16x8;
typedef __attribute__((ext_vector_type(4))) float f32x4;

__device__ __forceinline__ unsigned short f2bf(float f) {
    unsigned int u = __float_as_uint(f);
    unsigned int r = (u + 0x7fffu + ((u >> 16) & 1u)) >> 16;   // RNE
    return (unsigned short)r;
}

__device__ __forceinline__ void gload_lds16(const void* g, void* l) {
    __builtin_amdgcn_global_load_lds(
        (const __attribute__((address_space(1))) unsigned int*)g,
        (__attribute__((address_space(3))) unsigned int*)l, 16, 0, 0);
}

// ---------------------------------------------------------------------------
// conv_feat[b,t,c] = sum_k att[b, t+k-50] * ck[c,k]   (zero-padded)
// ---------------------------------------------------------------------------
__global__ void conv_kernel(const float* __restrict__ att,
                            const float* __restrict__ ck,
                            float* __restrict__ cf) {
    __shared__ float ck_s[CC * KW];
    int tid = threadIdx.x;
    for (int i = tid; i < CC * KW; i += blockDim.x) ck_s[i] = ck[i];
    __syncthreads();
    int b = blockIdx.y;
    int t = blockIdx.x * blockDim.x + tid;
    if (t >= TT) return;
    float acc[CC];
#pragma unroll
    for (int c = 0; c < CC; ++c) acc[c] = 0.f;
    const float* arow = att + b * TT;
    int k0 = PADW - t; if (k0 < 0) k0 = 0;
    int k1 = TT + PADW - t; if (k1 > KW) k1 = KW;
    for (int k = k0; k < k1; ++k) {
        float av = arow[t + k - PADW];
#pragma unroll
        for (int c = 0; c < CC; ++c) acc[c] = fmaf(av, ck_s[c * KW + k], acc[c]);
    }
    float* o = cf + (size_t)(b * TT + t) * CC;
#pragma unroll
    for (int c = 0; c < CC; ++c) o[c] = acc[c];
}

// ---------------------------------------------------------------------------
// dec_proj[b,a] = W_b[a] + sum_d dec[b,d] * W_w[D+d, a]
// ---------------------------------------------------------------------------
__global__ void decproj_kernel(const float* __restrict__ dec,
                               const float* __restrict__ Ww,
                               const float* __restrict__ Wb,
                               float* __restrict__ dp) {
    int b = blockIdx.x;
    int a = threadIdx.x;            // blockDim = 512
    const float* dr = dec + b * DD;
    const float* w = Ww + (size_t)DD * AA + a;
    float acc = Wb[a];
    for (int d = 0; d < DD; ++d) acc = fmaf(dr[d], w[(size_t)d * AA], acc);
    dp[b * AA + a] = acc;
}

// ---------------------------------------------------------------------------
// Pre-convert W1 (rows 0..1023 of W_w, fp32 [1024][512]) to bf16, laid out as
// 16 K-tiles of [512 cols][64 k] with the LDS image XOR-swizzle pre-applied,
// so the GEMM can stage each 64 KB tile with linear global_load_lds.
// dest byte within tile = col*128 + ((klocal*2) ^ ((col&7)<<4))
// ---------------------------------------------------------------------------
__global__ void wconv_kernel(const float* __restrict__ Ww,
                             unsigned short* __restrict__ Wt) {
    int g = blockIdx.x * 256 + threadIdx.x;     // 65536 threads
    int col = g & 511;
    int kg  = g >> 9;                           // 0..127, 8 k each
    int k   = kg * 8;
    u16x8 v;
#pragma unroll
    for (int i = 0; i < 8; ++i) v[i] = f2bf(Ww[(size_t)(k + i) * AA + col]);
    int ktile = k >> 6, klocal = k & 63;
    size_t byte = (size_t)ktile * 65536 + (size_t)col * 128 +
                  (size_t)((klocal * 2) ^ ((col & 7) << 4));
    *(u16x8*)((char*)Wt + byte) = v;
}

// ---------------------------------------------------------------------------
// energy[b,t] = 2 * sum_a tanh( enc@W1 + dp[b,a] + cf@Wc ) * V[a]
// MFMA bf16 GEMM: block = 128 rows x 512 cols x K64 tiles, 8 waves (2x4),
// wave tile 64x128 (4x8 fragments of 16x16x32). XOR-swizzled LDS.
// ---------------------------------------------------------------------------
__global__ __launch_bounds__(512, 2) void energy_mfma_kernel(
    const float* __restrict__ enc, const unsigned short* __restrict__ Wt,
    const float* __restrict__ Wc, const float* __restrict__ Vw,
    const float* __restrict__ dp, const float* __restrict__ cf,
    float* __restrict__ energy) {
    __shared__ __align__(16) char smem[81920];   // As 16KB | Bs 64KB
    char* As = smem;                // [128 rows][64 k] bf16, swizzled
    char* Bs = smem + 16384;        // [512 cols][64 k] bf16, swizzled

    int tid = threadIdx.x;
    int lane = tid & 63, wave = tid >> 6;
    int wm = wave >> 2, wn = wave & 3;          // 2 x 4 wave grid
    int b = blockIdx.y, t0 = blockIdx.x * 128;

    // A staging map: 4 threads/row, 16 k-elems each
    int arow = tid >> 2, akseg = tid & 3;
    int tg = t0 + arow; if (tg > TT - 1) tg = TT - 1;
    const float* asrc = enc + (size_t)(b * TT + tg) * DD + akseg * 16;
    int aswz = (arow & 7) << 4;
    int awb0 = arow * 128 + ((akseg * 32) ^ aswz);
    int awb1 = arow * 128 + ((akseg * 32 + 16) ^ aswz);

    f32x4 acc[4][8];
#pragma unroll
    for (int i = 0; i < 4; ++i)
#pragma unroll
        for (int j = 0; j < 8; ++j) acc[i][j] = (f32x4){0.f, 0.f, 0.f, 0.f};

    for (int kt = 0; kt < DD / 64; ++kt) {
        // A: global fp32 loads (issued before the barrier to overlap)
        const float* ap = asrc + kt * 64;
        float4 f0 = *(const float4*)(ap);
        float4 f1 = *(const float4*)(ap + 4);
        float4 f2 = *(const float4*)(ap + 8);
        float4 f3 = *(const float4*)(ap + 12);
        __syncthreads();            // previous iter's LDS reads complete
        u16x8 lo, hi;
        lo[0] = f2bf(f0.x); lo[1] = f2bf(f0.y); lo[2] = f2bf(f0.z); lo[3] = f2bf(f0.w);
        lo[4] = f2bf(f1.x); lo[5] = f2bf(f1.y); lo[6] = f2bf(f1.z); lo[7] = f2bf(f1.w);
        hi[0] = f2bf(f2.x); hi[1] = f2bf(f2.y); hi[2] = f2bf(f2.z); hi[3] = f2bf(f2.w);
        hi[4] = f2bf(f3.x); hi[5] = f2bf(f3.y); hi[6] = f2bf(f3.z); hi[7] = f2bf(f3.w);
        *(u16x8*)(As + awb0) = lo;
        *(u16x8*)(As + awb1) = hi;
        // B: 64 KB pre-swizzled tile via global_load_lds (linear dest)
        const char* bsrc = (const char*)Wt + (size_t)kt * 65536;
#pragma unroll
        for (int i = 0; i < 8; ++i) {
            int seg = (wave * 8 + i) * 1024;
            gload_lds16(bsrc + seg + lane * 16, Bs + seg);
        }
        __syncthreads();

#pragma unroll
        for (int ks = 0; ks < 2; ++ks) {
            int kb = ks * 64 + ((lane >> 4) * 16);
            bf16x8 af[4], bf[8];
#pragma unroll
            for (int mf = 0; mf < 4; ++mf) {
                int row = wm * 64 + mf * 16 + (lane & 15);
                af[mf] = *(bf16x8*)(As + row * 128 + (kb ^ ((row & 7) << 4)));
            }
#pragma unroll
            for (int nf = 0; nf < 8; ++nf) {
                int col = wn * 128 + nf * 16 + (lane & 15);
                bf[nf] = *(bf16x8*)(Bs + col * 128 + (kb ^ ((col & 7) << 4)));
            }
#pragma unroll
            for (int mf = 0; mf < 4; ++mf)
#pragma unroll
                for (int nf = 0; nf < 8; ++nf)
                    acc[mf][nf] = __builtin_amdgcn_mfma_f32_16x16x32_bf16(
                        af[mf], bf[nf], acc[mf][nf], 0, 0, 0);
        }
    }
    __syncthreads();

    // ---- epilogue: overlay epilogue tables onto the staging LDS ----
    float* Wc_s = (float*)smem;               // [10][512]
    float* dp_s = (float*)(smem + 20480);     // [512]
    float* V_s  = (float*)(smem + 22528);     // [512]
    float* cf_s = (float*)(smem + 24576);     // [128][10]
    float* part = (float*)(smem + 29696);     // [128][4]
    for (int i = tid; i < CC * AA; i += 512) Wc_s[i] = Wc[i];
    if (tid < AA) { dp_s[tid] = dp[b * AA + tid]; V_s[tid] = Vw[tid]; }
    for (int i = tid; i < 128 * CC; i += 512) {
        int rr = i / CC, c = i - rr * CC;
        int t = t0 + rr; int tc = t < TT ? t : TT - 1;
        cf_s[i] = cf[(size_t)(b * TT + tc) * CC + c];
    }
    __syncthreads();

    int lg = lane >> 4;     // 16-lane group -> D-row quad
#pragma unroll
    for (int mf = 0; mf < 4; ++mf) {
#pragma unroll
        for (int r = 0; r < 4; ++r) {
            int row = wm * 64 + mf * 16 + lg * 4 + r;
            float s = 0.f;
#pragma unroll
            for (int nf = 0; nf < 8; ++nf) {
                int col = wn * 128 + nf * 16 + (lane & 15);
                float v = acc[mf][nf][r] + dp_s[col];
#pragma unroll
                for (int c = 0; c < CC; ++c)
                    v = fmaf(cf_s[row * CC + c], Wc_s[c * AA + col], v);
                v = fminf(fmaxf(v, -30.f), 30.f);
                float ex = __expf(2.f * v);
                float th = (ex - 1.f) / (ex + 1.f);
                s = fmaf(th, V_s[col], s);
            }
            s += __shfl_xor(s, 1); s += __shfl_xor(s, 2);
            s += __shfl_xor(s, 4); s += __shfl_xor(s, 8);
            if ((lane & 15) == 0) part[row * 4 + wn] = s;
        }
    }
    __syncthreads();
    if (tid < 128) {
        float e = part[tid * 4] + part[tid * 4 + 1] +
                  part[tid * 4 + 2] + part[tid * 4 + 3];
        int t = t0 + tid;
        if (t < TT) energy[b * TT + t] = SHARP * e;
    }
}

// ---------------------------------------------------------------------------
// softmax over T per batch row
// ---------------------------------------------------------------------------
__global__ void softmax_kernel(const float* __restrict__ energy,
                               float* __restrict__ att) {
    int b = blockIdx.x, tid = threadIdx.x;
    const float* e = energy + b * TT;
    __shared__ float red[8];
    float m = -1e30f;
    for (int t = tid; t < TT; t += 256) m = fmaxf(m, e[t]);
#pragma unroll
    for (int s = 1; s < 64; s <<= 1) m = fmaxf(m, __shfl_xor(m, s));
    if ((tid & 63) == 0) red[tid >> 6] = m;
    __syncthreads();
    m = fmaxf(fmaxf(red[0], red[1]), fmaxf(red[2], red[3]));
    float s = 0.f;
    for (int t = tid; t < TT; t += 256) s += expf(e[t] - m);
#pragma unroll
    for (int sh = 1; sh < 64; sh <<= 1) s += __shfl_xor(s, sh);
    if ((tid & 63) == 0) red[4 + (tid >> 6)] = s;
    __syncthreads();
    s = red[4] + red[5] + red[6] + red[7];
    float inv = 1.f / s;
    for (int t = tid; t < TT; t += 256) att[b * TT + t] = expf(e[t] - m) * inv;
}

// ---------------------------------------------------------------------------
// context[b,d] = sum_t enc[b,t,d] * att[b,t]   (T split 12-way, atomicAdd)
// ---------------------------------------------------------------------------
#define TCH 125
__global__ void context_kernel(const float* __restrict__ enc,
                               const float* __restrict__ att,
                               float* __restrict__ ctx) {
    int b = blockIdx.x, ch = blockIdx.y;
    int d0 = threadIdx.x * 4;
    int ts = ch * TCH, te = ts + TCH; if (te > TT) te = TT;
    const float* ab = att + b * TT;
    float ax = 0.f, ay = 0.f, az = 0.f, aw = 0.f;
    for (int t = ts; t < te; ++t) {
        float w = ab[t];
        float4 ev = *(const float4*)&enc[(size_t)(b * TT + t) * DD + d0];
        ax = fmaf(w, ev.x, ax);
        ay = fmaf(w, ev.y, ay);
        az = fmaf(w, ev.z, az);
        aw = fmaf(w, ev.w, aw);
    }
    float* o = ctx + b * DD + d0;
    atomicAdd(&o[0], ax);
    atomicAdd(&o[1], ay);
    atomicAdd(&o[2], az);
    atomicAdd(&o[3], aw);
}

// ---------------------------------------------------------------------------
extern "C" void kernel_launch(void* const* d_in, const int* in_sizes, int n_in,
                              void* d_out, int out_size, void* d_ws, size_t ws_size,
                              hipStream_t stream) {
    const float* enc  = (const float*)d_in[0];
    const float* dec  = (const float*)d_in[1];
    const float* attw = (const float*)d_in[2];
    const float* Ww   = (const float*)d_in[3];
    const float* Wb   = (const float*)d_in[4];
    const float* Wc   = (const float*)d_in[5];
    const float* Vw   = (const float*)d_in[6];
    const float* ck   = (const float*)d_in[7];

    float* out = (float*)d_out;
    float* ctx = out;               // [B, D]
    float* att = out + BB * DD;     // [B, T]

    float* cf     = (float*)d_ws;                       // B*T*C
    float* dpb    = cf + (size_t)BB * TT * CC;          // B*A
    float* energy = dpb + (size_t)BB * AA;              // B*T
    unsigned short* Wt = (unsigned short*)(energy + (size_t)BB * TT); // 1 MB

    hipMemsetAsync(ctx, 0, (size_t)BB * DD * sizeof(float), stream);

    wconv_kernel<<<256, 256, 0, stream>>>(Ww, Wt);
    conv_kernel<<<dim3((TT + 255) / 256, BB), 256, 0, stream>>>(attw, ck, cf);
    decproj_kernel<<<BB, AA, 0, stream>>>(dec, Ww, Wb, dpb);
    energy_mfma_kernel<<<dim3(12, BB), 512, 0, stream>>>(
        enc, Wt, Wc, Vw, dpb, cf, energy);
    softmax_kernel<<<BB, 256, 0, stream>>>(energy, att);
    context_kernel<<<dim3(BB, 12), 256, 0, stream>>>(enc, att, ctx);
}